// Round 16
// baseline (303.875 us; speedup 1.0000x reference)
//
#include <hip/hip_runtime.h>

// SmallHGRNLM: V=50000, H=256, L=2, B=4, T=1024
// out = [B*T*V logits f32] ++ [L*B*H hiddens f32]

#define VV 50000
#define HH 256
#define LL 2
#define BB 4
#define TT 1024
#define MM 4096            // B*T
#define HID_OFF 204800000  // MM*VV

typedef __attribute__((ext_vector_type(8))) short short8_t;
typedef __attribute__((ext_vector_type(4))) short short4_t;
typedef __attribute__((ext_vector_type(4))) float f32x4_t;

static __device__ __forceinline__ short f2bf(float f) {
  union { float f; unsigned u; } a;
  a.f = f;
  unsigned u = a.u;
  unsigned r = u + 0x7fffu + ((u >> 16) & 1u);  // RNE
  return (short)(r >> 16);
}

// ---------------- embedding + bf16 cast ----------------
__global__ __launch_bounds__(256) void k_embed(const int* __restrict__ ids,
                                               const float* __restrict__ emb,
                                               float* __restrict__ x,
                                               short* __restrict__ xb) {
  int row = blockIdx.x;     // 0..4095
  int h = threadIdx.x;      // 0..255
  int id = ids[row];
  float v = emb[(size_t)id * HH + h];
  x[(size_t)row * HH + h] = v;
  xb[(size_t)row * HH + h] = f2bf(v);
}

// ---------------- L1: 3 gate GEMMs + per-chunk scan summaries ----------------
__global__ __launch_bounds__(256) void kL1(const short* __restrict__ xb,
                                           const float* __restrict__ Wi,
                                           const float* __restrict__ Wf,
                                           const float* __restrict__ Wg,
                                           const float* __restrict__ bi,
                                           const float* __restrict__ bfv,
                                           const float* __restrict__ bg,
                                           float* __restrict__ gall,
                                           float* __restrict__ P,
                                           float* __restrict__ S,
                                           float lower) {
  __shared__ __align__(16) short Alds[64][264];
  __shared__ __align__(16) short Wlds[64][264];
  __shared__ __align__(16) float Ilds[64][68];
  __shared__ __align__(16) float Flds[64][68];
  __shared__ __align__(16) float bsh3[192];

  int tid = threadIdx.x;
  int mt = blockIdx.x, nt = blockIdx.y;
  int m0 = mt * 64, n0 = nt * 64;

#pragma unroll
  for (int p = 0; p < 8; p++) {
    int idx = p * 256 + tid;
    int row = idx >> 5, ck = idx & 31;
    *(short8_t*)&Alds[row][ck * 8] =
        *(const short8_t*)(xb + (size_t)(m0 + row) * HH + ck * 8);
  }
  if (tid < 64) bsh3[tid] = bi[n0 + tid];
  else if (tid < 128) bsh3[tid] = bfv[n0 + tid - 64];
  else if (tid < 192) bsh3[tid] = bg[n0 + tid - 128];

  int lane = tid & 63, w = tid >> 6, wm = w >> 1, wn = w & 1;
  int r16 = lane & 15, kg = (lane >> 4) * 8;
  int cg = tid & 15, kr = tid >> 4;

  for (int gz = 0; gz < 3; gz++) {
    const float* W = (gz == 0) ? Wi : (gz == 1) ? Wf : Wg;
    float* dst = gall + (size_t)gz * (MM * HH);

    __syncthreads();  // Alds ready (iter0) / prev MFMA done with Wlds
#pragma unroll
    for (int p = 0; p < 16; p++) {
      int k = p * 16 + kr;
      float4 wv = *(const float4*)(W + (size_t)k * HH + n0 + cg * 4);
      Wlds[cg * 4 + 0][k] = f2bf(wv.x);
      Wlds[cg * 4 + 1][k] = f2bf(wv.y);
      Wlds[cg * 4 + 2][k] = f2bf(wv.z);
      Wlds[cg * 4 + 3][k] = f2bf(wv.w);
    }
    __syncthreads();

    f32x4_t acc[2][2] = {{{0.f,0.f,0.f,0.f},{0.f,0.f,0.f,0.f}},
                         {{0.f,0.f,0.f,0.f},{0.f,0.f,0.f,0.f}}};
#pragma unroll
    for (int kk = 0; kk < 8; kk++) {
      short8_t w0 = *(const short8_t*)&Wlds[wn * 32 + r16][kk * 32 + kg];
      short8_t w1 = *(const short8_t*)&Wlds[wn * 32 + 16 + r16][kk * 32 + kg];
      short8_t t0 = *(const short8_t*)&Alds[wm * 32 + r16][kk * 32 + kg];
      short8_t t1 = *(const short8_t*)&Alds[wm * 32 + 16 + r16][kk * 32 + kg];
      acc[0][0] = __builtin_amdgcn_mfma_f32_16x16x32_bf16(w0, t0, acc[0][0], 0, 0, 0);
      acc[0][1] = __builtin_amdgcn_mfma_f32_16x16x32_bf16(w0, t1, acc[0][1], 0, 0, 0);
      acc[1][0] = __builtin_amdgcn_mfma_f32_16x16x32_bf16(w1, t0, acc[1][0], 0, 0, 0);
      acc[1][1] = __builtin_amdgcn_mfma_f32_16x16x32_bf16(w1, t1, acc[1][1], 0, 0, 0);
    }
#pragma unroll
    for (int fv = 0; fv < 2; fv++)
#pragma unroll
      for (int ft = 0; ft < 2; ft++) {
        int tl = wm * 32 + ft * 16 + r16;                // token local 0..63
        int colb = wn * 32 + fv * 16 + (lane >> 4) * 4;  // h local 0..63
        f32x4_t z4 = acc[fv][ft] + *(const f32x4_t*)&bsh3[gz * 64 + colb];
        f32x4_t a4;
#pragma unroll
        for (int r = 0; r < 4; r++) {
          float z = z4[r];
          if (gz == 0) {
            a4[r] = z / (1.f + __expf(-z));                      // silu
          } else if (gz == 1) {
            a4[r] = lower + (1.f - lower) / (1.f + __expf(-z));  // bounded forget
          } else {
            a4[r] = 1.f / (1.f + __expf(-z));                    // sigmoid
          }
        }
        *(f32x4_t*)&dst[(size_t)(m0 + tl) * HH + n0 + colb] = a4;
        if (gz == 0) *(f32x4_t*)&Ilds[tl][colb] = a4;
        else if (gz == 1) *(f32x4_t*)&Flds[tl][colb] = a4;
      }
  }
  __syncthreads();  // Ilds/Flds complete

  if (tid < 128) {
    int chunk = tid >> 6, hl = tid & 63;
    float p = 1.f, s = 0.f;
#pragma unroll
    for (int t = 0; t < 32; t++) {
      float fv = Flds[chunk * 32 + t][hl];
      float iv = Ilds[chunk * 32 + t][hl];
      s = fv * s + (1.f - fv) * iv;
      p *= fv;
    }
    int b = mt >> 4;
    int c = (mt & 15) * 2 + chunk;
    int idx = (b * 32 + c) * HH + n0 + hl;
    P[idx] = p;
    S[idx] = s;
  }
}

// ---------------- scan pass 2+3 fused ----------------
__global__ __launch_bounds__(256) void k_scan23(const float* __restrict__ gall,
                                                const float* __restrict__ P,
                                                const float* __restrict__ S,
                                                short* __restrict__ hgb,
                                                float* __restrict__ hid,
                                                int l) {
  int bc = blockIdx.x;
  int b = bc >> 5, c = bc & 31;
  int h = threadIdx.x;
  float hv = 0.f;
  for (int cc = 0; cc < c; cc++) {
    int idx = (b * 32 + cc) * HH + h;
    hv = P[idx] * hv + S[idx];
  }
  const float* iptr = gall;
  const float* fptr = gall + (size_t)MM * HH;
  const float* gptr = gall + (size_t)2 * MM * HH;
  size_t base = (size_t)(b * TT + c * 32) * HH + h;
#pragma unroll 8
  for (int t = 0; t < 32; t++) {
    float fv = fptr[base + (size_t)t * HH];
    float iv = iptr[base + (size_t)t * HH];
    float gv = gptr[base + (size_t)t * HH];
    hv = fv * hv + (1.f - fv) * iv;
    hgb[base + (size_t)t * HH] = f2bf(hv * gv);
  }
  if (c == 31) hid[(size_t)(l * BB + b) * HH + h] = hv;
}

// ---------------- out projection: x += hg @ Wo + bo; refresh xb ----------------
__global__ __launch_bounds__(256) void k_wo(const short* __restrict__ hgb,
                                            const float* __restrict__ W,
                                            const float* __restrict__ bias,
                                            float* __restrict__ x,
                                            short* __restrict__ xb) {
  __shared__ __align__(16) short Alds[64][264];
  __shared__ __align__(16) short Wlds[64][264];
  __shared__ __align__(16) float bsh[64];

  int tid = threadIdx.x;
  int m0 = blockIdx.x * 64, n0 = blockIdx.y * 64;

  int cg = tid & 15, kr = tid >> 4;
#pragma unroll
  for (int p = 0; p < 16; p++) {
    int k = p * 16 + kr;
    float4 wv = *(const float4*)(W + (size_t)k * HH + n0 + cg * 4);
    Wlds[cg * 4 + 0][k] = f2bf(wv.x);
    Wlds[cg * 4 + 1][k] = f2bf(wv.y);
    Wlds[cg * 4 + 2][k] = f2bf(wv.z);
    Wlds[cg * 4 + 3][k] = f2bf(wv.w);
  }
  if (tid < 64) bsh[tid] = bias[n0 + tid];
#pragma unroll
  for (int p = 0; p < 8; p++) {
    int idx = p * 256 + tid;
    int row = idx >> 5, ck = idx & 31;
    *(short8_t*)&Alds[row][ck * 8] =
        *(const short8_t*)(hgb + (size_t)(m0 + row) * HH + ck * 8);
  }
  __syncthreads();

  int lane = tid & 63, w = tid >> 6, wm = w >> 1, wn = w & 1;
  int r16 = lane & 15, kg = (lane >> 4) * 8;
  f32x4_t acc[2][2] = {{{0.f,0.f,0.f,0.f},{0.f,0.f,0.f,0.f}},
                       {{0.f,0.f,0.f,0.f},{0.f,0.f,0.f,0.f}}};
#pragma unroll
  for (int kk = 0; kk < 8; kk++) {
    short8_t w0 = *(const short8_t*)&Wlds[wn * 32 + r16][kk * 32 + kg];
    short8_t w1 = *(const short8_t*)&Wlds[wn * 32 + 16 + r16][kk * 32 + kg];
    short8_t t0 = *(const short8_t*)&Alds[wm * 32 + r16][kk * 32 + kg];
    short8_t t1 = *(const short8_t*)&Alds[wm * 32 + 16 + r16][kk * 32 + kg];
    acc[0][0] = __builtin_amdgcn_mfma_f32_16x16x32_bf16(w0, t0, acc[0][0], 0, 0, 0);
    acc[0][1] = __builtin_amdgcn_mfma_f32_16x16x32_bf16(w0, t1, acc[0][1], 0, 0, 0);
    acc[1][0] = __builtin_amdgcn_mfma_f32_16x16x32_bf16(w1, t0, acc[1][0], 0, 0, 0);
    acc[1][1] = __builtin_amdgcn_mfma_f32_16x16x32_bf16(w1, t1, acc[1][1], 0, 0, 0);
  }
#pragma unroll
  for (int fv = 0; fv < 2; fv++)
#pragma unroll
    for (int ft = 0; ft < 2; ft++) {
      int token = m0 + wm * 32 + ft * 16 + r16;
      int colb = wn * 32 + fv * 16 + (lane >> 4) * 4;
      size_t idx = (size_t)token * HH + n0 + colb;
      f32x4_t xv = *(const f32x4_t*)&x[idx];
      xv += acc[fv][ft] + *(const f32x4_t*)&bsh[colb];
      *(f32x4_t*)&x[idx] = xv;
      short4_t xb4;
#pragma unroll
      for (int r = 0; r < 4; r++) xb4[r] = f2bf(xv[r]);
      *(short4_t*)&xb[idx] = xb4;
    }
}

// ---------------- final projection: out = xb @ Wp + bp ----------------
// grid: (196 n-supertiles of 256 cols, 2 msplits), block 512 (8 waves).
// R14 structure; single-variable A/B vs R14: readout uses REGULAR stores
// (full 128B lines in 1KB contiguous runs -> no partial-line RFO; the fill
// kernel's 6.5 TB/s pattern) instead of nontemporal.
__global__ __launch_bounds__(512) void k_proj(const short* __restrict__ xb,
                                              const float* __restrict__ Wp,
                                              const float* __restrict__ bp,
                                              float* __restrict__ out) {
  __shared__ __align__(16) short Alds[64][264];
  __shared__ __align__(16) float Ost[64][260];   // 66.6KB; W-stage reuses this
  __shared__ __align__(16) float bsh[256];

  short (*Wst)[264] = (short(*)[264])&Ost[0][0]; // 33.8KB fits inside Ost

  int tid = threadIdx.x;
  int n0 = blockIdx.x * 256;

  int lane = tid & 63, w = tid >> 6;        // 8 waves
  int wm = w >> 2, wq = w & 3;              // wm: token half (32), wq: col quarter (64)
  int r16 = lane & 15, kg = (lane >> 4) * 8;
  int cg = tid & 15, kr = tid >> 4;         // kr 0..31

  if (tid < 256) bsh[tid] = (n0 + tid < VV) ? bp[n0 + tid] : 0.f;

  // stage + hoist W: four 64-col slabs sequentially through Wst
  short8_t wf[8][4];
  for (int s = 0; s < 4; s++) {
    int c0 = n0 + s * 64;
    bool fullslab = (c0 + 64 <= VV);
#pragma unroll
    for (int p = 0; p < 8; p++) {
      int k = p * 32 + kr;
      if (fullslab) {
        float4 wv = *(const float4*)(Wp + (size_t)k * VV + c0 + cg * 4);
        Wst[cg * 4 + 0][k] = f2bf(wv.x);
        Wst[cg * 4 + 1][k] = f2bf(wv.y);
        Wst[cg * 4 + 2][k] = f2bf(wv.z);
        Wst[cg * 4 + 3][k] = f2bf(wv.w);
      } else {
        for (int j = 0; j < 4; j++) {
          int n = c0 + cg * 4 + j;
          float v = (n < VV) ? Wp[(size_t)k * VV + n] : 0.f;
          Wst[cg * 4 + j][k] = f2bf(v);
        }
      }
    }
    __syncthreads();
    if (wq == s) {
#pragma unroll
      for (int kk = 0; kk < 8; kk++)
#pragma unroll
        for (int cf = 0; cf < 4; cf++)
          wf[kk][cf] = *(const short8_t*)&Wst[cf * 16 + r16][kk * 32 + kg];
    }
    asm volatile("s_waitcnt lgkmcnt(0)" ::: "memory");
    __syncthreads();
  }

  int arow = tid >> 5;       // 0..15; A stage rows arow + 16p
  int ack = tid & 31;

  const int NMT = 32;  // 2 msplits * 32 * 64 = 4096 = MM
  int mbase = blockIdx.y * NMT * 64;

  short8_t areg[4];
#pragma unroll
  for (int p = 0; p < 4; p++)
    areg[p] = *(const short8_t*)(xb + (size_t)(mbase + p * 16 + arow) * HH + ack * 8);

  for (int mi = 0; mi < NMT; mi++) {
    int m0 = mbase + mi * 64;

    // barrier A: prev MFMA done with Alds; prev readout done with Ost.
    __builtin_amdgcn_sched_barrier(0);
    __builtin_amdgcn_s_barrier();
    __builtin_amdgcn_sched_barrier(0);

#pragma unroll
    for (int p = 0; p < 4; p++)
      *(short8_t*)&Alds[p * 16 + arow][ack * 8] = areg[p];

    // barrier B: Alds visible; lgkmcnt only (stores keep streaming).
    asm volatile("s_waitcnt lgkmcnt(0)" ::: "memory");
    __builtin_amdgcn_sched_barrier(0);
    __builtin_amdgcn_s_barrier();
    __builtin_amdgcn_sched_barrier(0);

    if (mi + 1 < NMT) {
      int m1 = m0 + 64;
#pragma unroll
      for (int p = 0; p < 4; p++)
        areg[p] = *(const short8_t*)(xb + (size_t)(m1 + p * 16 + arow) * HH + ack * 8);
    }

    f32x4_t acc[2][4] = {{{0.f,0.f,0.f,0.f},{0.f,0.f,0.f,0.f},
                          {0.f,0.f,0.f,0.f},{0.f,0.f,0.f,0.f}},
                         {{0.f,0.f,0.f,0.f},{0.f,0.f,0.f,0.f},
                          {0.f,0.f,0.f,0.f},{0.f,0.f,0.f,0.f}}};
#pragma unroll
    for (int kk = 0; kk < 8; kk++) {
      short8_t t0 = *(const short8_t*)&Alds[wm * 32 + r16][kk * 32 + kg];
      short8_t t1 = *(const short8_t*)&Alds[wm * 32 + 16 + r16][kk * 32 + kg];
#pragma unroll
      for (int cf = 0; cf < 4; cf++) {
        acc[0][cf] = __builtin_amdgcn_mfma_f32_16x16x32_bf16(wf[kk][cf], t0, acc[0][cf], 0, 0, 0);
        acc[1][cf] = __builtin_amdgcn_mfma_f32_16x16x32_bf16(wf[kk][cf], t1, acc[1][cf], 0, 0, 0);
      }
    }

    // epilogue: stage acc into Ost[tok][col]
#pragma unroll
    for (int ft = 0; ft < 2; ft++)
#pragma unroll
      for (int cf = 0; cf < 4; cf++) {
        int tok = wm * 32 + ft * 16 + r16;
        int col = wq * 64 + cf * 16 + (lane >> 4) * 4;
        *(f32x4_t*)&Ost[tok][col] = acc[ft][cf];
      }
    // barrier C: Ost visible; lgkmcnt only.
    asm volatile("s_waitcnt lgkmcnt(0)" ::: "memory");
    __builtin_amdgcn_sched_barrier(0);
    __builtin_amdgcn_s_barrier();
    __builtin_amdgcn_sched_barrier(0);

    // readout: wave w covers rows w*8..w*8+7; each wave-store instruction
    // writes ONE ROW x 1KB contiguous (64 lanes x 16B). REGULAR stores (A/B).
    int colc = lane * 4;
    bool colok = (n0 + colc < VV);
#pragma unroll
    for (int r = 0; r < 8; r++) {
      int row = w * 8 + r;
      f32x4_t v = *(const f32x4_t*)&Ost[row][colc] + *(const f32x4_t*)&bsh[colc];
      if (colok)
        *(f32x4_t*)(out + (size_t)(m0 + row) * VV + n0 + colc) = v;
    }
  }
}

extern "C" void kernel_launch(void* const* d_in, const int* in_sizes, int n_in,
                              void* d_out, int out_size, void* d_ws, size_t ws_size,
                              hipStream_t stream) {
  const int* ids = (const int*)d_in[0];
  const float* emb = (const float*)d_in[1];
  const float* Wi = (const float*)d_in[2];
  const float* bi = (const float*)d_in[3];
  const float* Wf = (const float*)d_in[4];
  const float* bfv = (const float*)d_in[5];
  const float* Wg = (const float*)d_in[6];
  const float* bg = (const float*)d_in[7];
  const float* Wo = (const float*)d_in[8];
  const float* bo = (const float*)d_in[9];
  const float* Wp = (const float*)d_in[10];
  const float* bp = (const float*)d_in[11];
  float* out = (float*)d_out;

  // workspace layout (~20.5 MB)
  char* w = (char*)d_ws;
  float* x = (float*)(w);                          // 4 MB
  short* xb = (short*)(w + (4u << 20));            // 2 MB
  float* gall = (float*)(w + (6u << 20));          // 12 MB: [3][4096][256] (i,f,g)
  short* hgb = (short*)(w + (18u << 20));          // 2 MB
  float* Parr = (float*)(w + (20u << 20));         // 128 KB
  float* Sarr = (float*)(w + (20u << 20) + (128u << 10));
  float* hid = out + HID_OFF;

  k_embed<<<MM, 256, 0, stream>>>(ids, emb, x, xb);

  for (int l = 0; l < LL; l++) {
    float lower = (float)l / (float)LL;
    kL1<<<dim3(64, 4), 256, 0, stream>>>(
        xb, Wi + (size_t)l * HH * HH, Wf + (size_t)l * HH * HH,
        Wg + (size_t)l * HH * HH, bi + l * HH, bfv + l * HH, bg + l * HH,
        gall, Parr, Sarr, lower);
    k_scan23<<<BB * 32, 256, 0, stream>>>(gall, Parr, Sarr, hgb, hid, l);
    k_wo<<<dim3(64, 4), 256, 0, stream>>>(hgb, Wo + (size_t)l * HH * HH,
                                          bo + l * HH, x, xb);
  }

  k_proj<<<dim3(196, 2), 512, 0, stream>>>(xb, Wp, bp, out);
}

// Round 17
// 265.237 us; speedup vs baseline: 1.1457x; 1.1457x over previous
//
#include <hip/hip_runtime.h>

// SmallHGRNLM: V=50000, H=256, L=2, B=4, T=1024
// out = [B*T*V logits f32] ++ [L*B*H hiddens f32]

#define VV 50000
#define HH 256
#define LL 2
#define BB 4
#define TT 1024
#define MM 4096            // B*T
#define HID_OFF 204800000  // MM*VV

typedef __attribute__((ext_vector_type(8))) short short8_t;
typedef __attribute__((ext_vector_type(4))) short short4_t;
typedef __attribute__((ext_vector_type(4))) float f32x4_t;

static __device__ __forceinline__ short f2bf(float f) {
  union { float f; unsigned u; } a;
  a.f = f;
  unsigned u = a.u;
  unsigned r = u + 0x7fffu + ((u >> 16) & 1u);  // RNE
  return (short)(r >> 16);
}

// ---------------- L1: 3 gate GEMMs + per-chunk scan summaries ----------------
// grid (64 mtiles, 4 ntiles), block 256. layer0: stage A straight from the
// embedding gather (emb f32 -> bf16) and write x (nt-partitioned cols) — the
// separate k_embed kernel and the xb round-trip are gone for layer 0.
__global__ __launch_bounds__(256) void kL1(const short* __restrict__ xb,
                                           const int* __restrict__ ids,
                                           const float* __restrict__ emb,
                                           float* __restrict__ x,
                                           const float* __restrict__ Wi,
                                           const float* __restrict__ Wf,
                                           const float* __restrict__ Wg,
                                           const float* __restrict__ bi,
                                           const float* __restrict__ bfv,
                                           const float* __restrict__ bg,
                                           float* __restrict__ gall,
                                           float* __restrict__ P,
                                           float* __restrict__ S,
                                           float lower, int layer0) {
  __shared__ __align__(16) short Alds[64][264];
  __shared__ __align__(16) short Wlds[64][264];
  __shared__ __align__(16) float Ilds[64][68];
  __shared__ __align__(16) float Flds[64][68];
  __shared__ __align__(16) float bsh3[192];

  int tid = threadIdx.x;
  int mt = blockIdx.x, nt = blockIdx.y;
  int m0 = mt * 64, n0 = nt * 64;

  if (layer0) {
#pragma unroll
    for (int p = 0; p < 8; p++) {
      int idx = p * 256 + tid;
      int row = idx >> 5, ck = idx & 31;   // cols ck*8..ck*8+7
      int id = ids[m0 + row];
      float4 e0 = *(const float4*)(emb + (size_t)id * HH + ck * 8);
      float4 e1 = *(const float4*)(emb + (size_t)id * HH + ck * 8 + 4);
      short8_t a8;
      a8[0] = f2bf(e0.x); a8[1] = f2bf(e0.y); a8[2] = f2bf(e0.z); a8[3] = f2bf(e0.w);
      a8[4] = f2bf(e1.x); a8[5] = f2bf(e1.y); a8[6] = f2bf(e1.z); a8[7] = f2bf(e1.w);
      *(short8_t*)&Alds[row][ck * 8] = a8;
      if ((ck >> 3) == nt) {  // exact col partition across nt blocks
        *(float4*)(x + (size_t)(m0 + row) * HH + ck * 8) = e0;
        *(float4*)(x + (size_t)(m0 + row) * HH + ck * 8 + 4) = e1;
      }
    }
  } else {
#pragma unroll
    for (int p = 0; p < 8; p++) {
      int idx = p * 256 + tid;
      int row = idx >> 5, ck = idx & 31;
      *(short8_t*)&Alds[row][ck * 8] =
          *(const short8_t*)(xb + (size_t)(m0 + row) * HH + ck * 8);
    }
  }
  if (tid < 64) bsh3[tid] = bi[n0 + tid];
  else if (tid < 128) bsh3[tid] = bfv[n0 + tid - 64];
  else if (tid < 192) bsh3[tid] = bg[n0 + tid - 128];

  int lane = tid & 63, w = tid >> 6, wm = w >> 1, wn = w & 1;
  int r16 = lane & 15, kg = (lane >> 4) * 8;
  int cg = tid & 15, kr = tid >> 4;

  for (int gz = 0; gz < 3; gz++) {
    const float* W = (gz == 0) ? Wi : (gz == 1) ? Wf : Wg;
    float* dst = gall + (size_t)gz * (MM * HH);

    __syncthreads();  // Alds ready (iter0) / prev MFMA done with Wlds
#pragma unroll
    for (int p = 0; p < 16; p++) {
      int k = p * 16 + kr;
      float4 wv = *(const float4*)(W + (size_t)k * HH + n0 + cg * 4);
      Wlds[cg * 4 + 0][k] = f2bf(wv.x);
      Wlds[cg * 4 + 1][k] = f2bf(wv.y);
      Wlds[cg * 4 + 2][k] = f2bf(wv.z);
      Wlds[cg * 4 + 3][k] = f2bf(wv.w);
    }
    __syncthreads();

    f32x4_t acc[2][2] = {{{0.f,0.f,0.f,0.f},{0.f,0.f,0.f,0.f}},
                         {{0.f,0.f,0.f,0.f},{0.f,0.f,0.f,0.f}}};
#pragma unroll
    for (int kk = 0; kk < 8; kk++) {
      short8_t w0 = *(const short8_t*)&Wlds[wn * 32 + r16][kk * 32 + kg];
      short8_t w1 = *(const short8_t*)&Wlds[wn * 32 + 16 + r16][kk * 32 + kg];
      short8_t t0 = *(const short8_t*)&Alds[wm * 32 + r16][kk * 32 + kg];
      short8_t t1 = *(const short8_t*)&Alds[wm * 32 + 16 + r16][kk * 32 + kg];
      acc[0][0] = __builtin_amdgcn_mfma_f32_16x16x32_bf16(w0, t0, acc[0][0], 0, 0, 0);
      acc[0][1] = __builtin_amdgcn_mfma_f32_16x16x32_bf16(w0, t1, acc[0][1], 0, 0, 0);
      acc[1][0] = __builtin_amdgcn_mfma_f32_16x16x32_bf16(w1, t0, acc[1][0], 0, 0, 0);
      acc[1][1] = __builtin_amdgcn_mfma_f32_16x16x32_bf16(w1, t1, acc[1][1], 0, 0, 0);
    }
#pragma unroll
    for (int fv = 0; fv < 2; fv++)
#pragma unroll
      for (int ft = 0; ft < 2; ft++) {
        int tl = wm * 32 + ft * 16 + r16;                // token local 0..63
        int colb = wn * 32 + fv * 16 + (lane >> 4) * 4;  // h local 0..63
        f32x4_t z4 = acc[fv][ft] + *(const f32x4_t*)&bsh3[gz * 64 + colb];
        f32x4_t a4;
#pragma unroll
        for (int r = 0; r < 4; r++) {
          float z = z4[r];
          if (gz == 0) {
            a4[r] = z / (1.f + __expf(-z));                      // silu
          } else if (gz == 1) {
            a4[r] = lower + (1.f - lower) / (1.f + __expf(-z));  // bounded forget
          } else {
            a4[r] = 1.f / (1.f + __expf(-z));                    // sigmoid
          }
        }
        *(f32x4_t*)&dst[(size_t)(m0 + tl) * HH + n0 + colb] = a4;
        if (gz == 0) *(f32x4_t*)&Ilds[tl][colb] = a4;
        else if (gz == 1) *(f32x4_t*)&Flds[tl][colb] = a4;
      }
  }
  __syncthreads();  // Ilds/Flds complete

  if (tid < 128) {
    int chunk = tid >> 6, hl = tid & 63;
    float p = 1.f, s = 0.f;
#pragma unroll
    for (int t = 0; t < 32; t++) {
      float fv = Flds[chunk * 32 + t][hl];
      float iv = Ilds[chunk * 32 + t][hl];
      s = fv * s + (1.f - fv) * iv;
      p *= fv;
    }
    int b = mt >> 4;
    int c = (mt & 15) * 2 + chunk;
    int idx = (b * 32 + c) * HH + n0 + hl;
    P[idx] = p;
    S[idx] = s;
  }
}

// ---------------- scan pass 2+3 fused ----------------
// grid 256 blocks (b, c, h-half), block 128: full CU coverage (was 128 blocks).
__global__ __launch_bounds__(128) void k_scan23(const float* __restrict__ gall,
                                                const float* __restrict__ P,
                                                const float* __restrict__ S,
                                                short* __restrict__ hgb,
                                                float* __restrict__ hid,
                                                int l) {
  int bid = blockIdx.x;
  int b = bid >> 6, c = (bid >> 1) & 31, half = bid & 1;
  int h = half * 128 + threadIdx.x;
  float hv = 0.f;
  for (int cc = 0; cc < c; cc++) {
    int idx = (b * 32 + cc) * HH + h;
    hv = P[idx] * hv + S[idx];
  }
  const float* iptr = gall;
  const float* fptr = gall + (size_t)MM * HH;
  const float* gptr = gall + (size_t)2 * MM * HH;
  size_t base = (size_t)(b * TT + c * 32) * HH + h;
#pragma unroll 8
  for (int t = 0; t < 32; t++) {
    float fv = fptr[base + (size_t)t * HH];
    float iv = iptr[base + (size_t)t * HH];
    float gv = gptr[base + (size_t)t * HH];
    hv = fv * hv + (1.f - fv) * iv;
    hgb[base + (size_t)t * HH] = f2bf(hv * gv);
  }
  if (c == 31) hid[(size_t)(l * BB + b) * HH + h] = hv;
}

// ---------------- out projection: x += hg @ Wo + bo; refresh xb ----------------
__global__ __launch_bounds__(256) void k_wo(const short* __restrict__ hgb,
                                            const float* __restrict__ W,
                                            const float* __restrict__ bias,
                                            float* __restrict__ x,
                                            short* __restrict__ xb) {
  __shared__ __align__(16) short Alds[64][264];
  __shared__ __align__(16) short Wlds[64][264];
  __shared__ __align__(16) float bsh[64];

  int tid = threadIdx.x;
  int m0 = blockIdx.x * 64, n0 = blockIdx.y * 64;

  int cg = tid & 15, kr = tid >> 4;
#pragma unroll
  for (int p = 0; p < 16; p++) {
    int k = p * 16 + kr;
    float4 wv = *(const float4*)(W + (size_t)k * HH + n0 + cg * 4);
    Wlds[cg * 4 + 0][k] = f2bf(wv.x);
    Wlds[cg * 4 + 1][k] = f2bf(wv.y);
    Wlds[cg * 4 + 2][k] = f2bf(wv.z);
    Wlds[cg * 4 + 3][k] = f2bf(wv.w);
  }
  if (tid < 64) bsh[tid] = bias[n0 + tid];
#pragma unroll
  for (int p = 0; p < 8; p++) {
    int idx = p * 256 + tid;
    int row = idx >> 5, ck = idx & 31;
    *(short8_t*)&Alds[row][ck * 8] =
        *(const short8_t*)(hgb + (size_t)(m0 + row) * HH + ck * 8);
  }
  __syncthreads();

  int lane = tid & 63, w = tid >> 6, wm = w >> 1, wn = w & 1;
  int r16 = lane & 15, kg = (lane >> 4) * 8;
  f32x4_t acc[2][2] = {{{0.f,0.f,0.f,0.f},{0.f,0.f,0.f,0.f}},
                       {{0.f,0.f,0.f,0.f},{0.f,0.f,0.f,0.f}}};
#pragma unroll
  for (int kk = 0; kk < 8; kk++) {
    short8_t w0 = *(const short8_t*)&Wlds[wn * 32 + r16][kk * 32 + kg];
    short8_t w1 = *(const short8_t*)&Wlds[wn * 32 + 16 + r16][kk * 32 + kg];
    short8_t t0 = *(const short8_t*)&Alds[wm * 32 + r16][kk * 32 + kg];
    short8_t t1 = *(const short8_t*)&Alds[wm * 32 + 16 + r16][kk * 32 + kg];
    acc[0][0] = __builtin_amdgcn_mfma_f32_16x16x32_bf16(w0, t0, acc[0][0], 0, 0, 0);
    acc[0][1] = __builtin_amdgcn_mfma_f32_16x16x32_bf16(w0, t1, acc[0][1], 0, 0, 0);
    acc[1][0] = __builtin_amdgcn_mfma_f32_16x16x32_bf16(w1, t0, acc[1][0], 0, 0, 0);
    acc[1][1] = __builtin_amdgcn_mfma_f32_16x16x32_bf16(w1, t1, acc[1][1], 0, 0, 0);
  }
#pragma unroll
  for (int fv = 0; fv < 2; fv++)
#pragma unroll
    for (int ft = 0; ft < 2; ft++) {
      int token = m0 + wm * 32 + ft * 16 + r16;
      int colb = wn * 32 + fv * 16 + (lane >> 4) * 4;
      size_t idx = (size_t)token * HH + n0 + colb;
      f32x4_t xv = *(const f32x4_t*)&x[idx];
      xv += acc[fv][ft] + *(const f32x4_t*)&bsh[colb];
      *(f32x4_t*)&x[idx] = xv;
      short4_t xb4;
#pragma unroll
      for (int r = 0; r < 4; r++) xb4[r] = f2bf(xv[r]);
      *(short4_t*)&xb[idx] = xb4;
    }
}

// ---------------- final projection: out = xb @ Wp + bp ----------------
// grid: (196 supertiles x 256 cols, 2 msplits), block 512 (8 waves). R14's
// geometry, restructured to 2 barrier-phases/iteration so NT-store issue
// (DRAM-drain-rate-bound) overlaps ALL compute:
//   X: A-write(i) + readout/stores of Ost(i-1)  |barrier|
//   Y: MFMA(i) reads Alds, writes Ost(i)        |barrier|
// Single Ost buffer is legal: X's reads and Y's writes are barrier-separated.
__global__ __launch_bounds__(512) void k_proj(const short* __restrict__ xb,
                                              const float* __restrict__ Wp,
                                              const float* __restrict__ bp,
                                              float* __restrict__ out) {
  __shared__ __align__(16) short Alds[64][264];
  __shared__ __align__(16) float Ost[64][260];   // 66.6KB; W-stage reuses this
  __shared__ __align__(16) float bsh[256];

  short (*Wst)[264] = (short(*)[264])&Ost[0][0]; // 33.8KB fits inside Ost

  int tid = threadIdx.x;
  int n0 = blockIdx.x * 256;

  int lane = tid & 63, w = tid >> 6;        // 8 waves
  int wm = w >> 2, wq = w & 3;              // wm: token half, wq: col quarter
  int r16 = lane & 15, kg = (lane >> 4) * 8;
  int cg = tid & 15, kr = tid >> 4;         // kr 0..31

  if (tid < 256) bsh[tid] = (n0 + tid < VV) ? bp[n0 + tid] : 0.f;

  // stage + hoist W: four 64-col slabs sequentially through Wst
  short8_t wf[8][4];
  for (int s = 0; s < 4; s++) {
    int c0 = n0 + s * 64;
    bool fullslab = (c0 + 64 <= VV);
#pragma unroll
    for (int p = 0; p < 8; p++) {
      int k = p * 32 + kr;
      if (fullslab) {
        float4 wv = *(const float4*)(Wp + (size_t)k * VV + c0 + cg * 4);
        Wst[cg * 4 + 0][k] = f2bf(wv.x);
        Wst[cg * 4 + 1][k] = f2bf(wv.y);
        Wst[cg * 4 + 2][k] = f2bf(wv.z);
        Wst[cg * 4 + 3][k] = f2bf(wv.w);
      } else {
        for (int j = 0; j < 4; j++) {
          int n = c0 + cg * 4 + j;
          float v = (n < VV) ? Wp[(size_t)k * VV + n] : 0.f;
          Wst[cg * 4 + j][k] = f2bf(v);
        }
      }
    }
    __syncthreads();
    if (wq == s) {
#pragma unroll
      for (int kk = 0; kk < 8; kk++)
#pragma unroll
        for (int cf = 0; cf < 4; cf++)
          wf[kk][cf] = *(const short8_t*)&Wst[cf * 16 + r16][kk * 32 + kg];
    }
    asm volatile("s_waitcnt lgkmcnt(0)" ::: "memory");
    __syncthreads();
  }

  int arow = tid >> 5;       // 0..15; A stage rows arow + 16p
  int ack = tid & 31;
  int colc = lane * 4;       // readout col within supertile
  bool colok = (n0 + colc < VV);

  const int NMT = 32;  // 2 msplits * 32 * 64 = 4096 = MM
  int mbase = blockIdx.y * NMT * 64;

  short8_t areg[4];
#pragma unroll
  for (int p = 0; p < 4; p++)
    areg[p] = *(const short8_t*)(xb + (size_t)(mbase + p * 16 + arow) * HH + ack * 8);

  int m_prev = -1;
  for (int mi = 0; mi < NMT; mi++) {
    int m0 = mbase + mi * 64;

    // ---- Phase X: A-write(i) + readout/stores of Ost(i-1) ----
#pragma unroll
    for (int p = 0; p < 4; p++)
      *(short8_t*)&Alds[p * 16 + arow][ack * 8] = areg[p];

    if (m_prev >= 0) {
#pragma unroll
      for (int r = 0; r < 8; r++) {
        int row = w * 8 + r;
        f32x4_t v = *(const f32x4_t*)&Ost[row][colc] + *(const f32x4_t*)&bsh[colc];
        if (colok)
          __builtin_nontemporal_store(v,
              (f32x4_t*)(out + (size_t)(m_prev + row) * VV + n0 + colc));
      }
    }

    asm volatile("s_waitcnt lgkmcnt(0)" ::: "memory");
    __builtin_amdgcn_sched_barrier(0);
    __builtin_amdgcn_s_barrier();
    __builtin_amdgcn_sched_barrier(0);

    // ---- Phase Y: MFMA(i) + Ost-write(i) ----
    if (mi + 1 < NMT) {
      int m1 = m0 + 64;
#pragma unroll
      for (int p = 0; p < 4; p++)
        areg[p] = *(const short8_t*)(xb + (size_t)(m1 + p * 16 + arow) * HH + ack * 8);
    }

    f32x4_t acc[2][4] = {{{0.f,0.f,0.f,0.f},{0.f,0.f,0.f,0.f},
                          {0.f,0.f,0.f,0.f},{0.f,0.f,0.f,0.f}},
                         {{0.f,0.f,0.f,0.f},{0.f,0.f,0.f,0.f},
                          {0.f,0.f,0.f,0.f},{0.f,0.f,0.f,0.f}}};
#pragma unroll
    for (int kk = 0; kk < 8; kk++) {
      short8_t t0 = *(const short8_t*)&Alds[wm * 32 + r16][kk * 32 + kg];
      short8_t t1 = *(const short8_t*)&Alds[wm * 32 + 16 + r16][kk * 32 + kg];
#pragma unroll
      for (int cf = 0; cf < 4; cf++) {
        acc[0][cf] = __builtin_amdgcn_mfma_f32_16x16x32_bf16(wf[kk][cf], t0, acc[0][cf], 0, 0, 0);
        acc[1][cf] = __builtin_amdgcn_mfma_f32_16x16x32_bf16(wf[kk][cf], t1, acc[1][cf], 0, 0, 0);
      }
    }
#pragma unroll
    for (int ft = 0; ft < 2; ft++)
#pragma unroll
      for (int cf = 0; cf < 4; cf++) {
        int tok = wm * 32 + ft * 16 + r16;
        int col = wq * 64 + cf * 16 + (lane >> 4) * 4;
        *(f32x4_t*)&Ost[tok][col] = acc[ft][cf];
      }

    asm volatile("s_waitcnt lgkmcnt(0)" ::: "memory");
    __builtin_amdgcn_sched_barrier(0);
    __builtin_amdgcn_s_barrier();
    __builtin_amdgcn_sched_barrier(0);

    m_prev = m0;
  }

  // epilogue: readout last tile
#pragma unroll
  for (int r = 0; r < 8; r++) {
    int row = w * 8 + r;
    f32x4_t v = *(const f32x4_t*)&Ost[row][colc] + *(const f32x4_t*)&bsh[colc];
    if (colok)
      __builtin_nontemporal_store(v,
          (f32x4_t*)(out + (size_t)(m_prev + row) * VV + n0 + colc));
  }
}

extern "C" void kernel_launch(void* const* d_in, const int* in_sizes, int n_in,
                              void* d_out, int out_size, void* d_ws, size_t ws_size,
                              hipStream_t stream) {
  const int* ids = (const int*)d_in[0];
  const float* emb = (const float*)d_in[1];
  const float* Wi = (const float*)d_in[2];
  const float* bi = (const float*)d_in[3];
  const float* Wf = (const float*)d_in[4];
  const float* bfv = (const float*)d_in[5];
  const float* Wg = (const float*)d_in[6];
  const float* bg = (const float*)d_in[7];
  const float* Wo = (const float*)d_in[8];
  const float* bo = (const float*)d_in[9];
  const float* Wp = (const float*)d_in[10];
  const float* bp = (const float*)d_in[11];
  float* out = (float*)d_out;

  // workspace layout (~20.5 MB)
  char* w = (char*)d_ws;
  float* x = (float*)(w);                          // 4 MB
  short* xb = (short*)(w + (4u << 20));            // 2 MB
  float* gall = (float*)(w + (6u << 20));          // 12 MB: [3][4096][256] (i,f,g)
  short* hgb = (short*)(w + (18u << 20));          // 2 MB
  float* Parr = (float*)(w + (20u << 20));         // 128 KB
  float* Sarr = (float*)(w + (20u << 20) + (128u << 10));
  float* hid = out + HID_OFF;

  for (int l = 0; l < LL; l++) {
    float lower = (float)l / (float)LL;
    kL1<<<dim3(64, 4), 256, 0, stream>>>(
        xb, ids, emb, x,
        Wi + (size_t)l * HH * HH, Wf + (size_t)l * HH * HH,
        Wg + (size_t)l * HH * HH, bi + l * HH, bfv + l * HH, bg + l * HH,
        gall, Parr, Sarr, lower, l == 0 ? 1 : 0);
    k_scan23<<<256, 128, 0, stream>>>(gall, Parr, Sarr, hgb, hid, l);
    k_wo<<<dim3(64, 4), 256, 0, stream>>>(hgb, Wo + (size_t)l * HH * HH,
                                          bo + l * HH, x, xb);
  }

  k_proj<<<dim3(196, 2), 512, 0, stream>>>(xb, Wp, bp, out);
}

// Round 18
// 258.276 us; speedup vs baseline: 1.1766x; 1.0270x over previous
//
#include <hip/hip_runtime.h>

// SmallHGRNLM: V=50000, H=256, L=2, B=4, T=1024
// out = [B*T*V logits f32] ++ [L*B*H hiddens f32]

#define VV 50000
#define HH 256
#define LL 2
#define BB 4
#define TT 1024
#define MM 4096            // B*T
#define HID_OFF 204800000  // MM*VV

typedef __attribute__((ext_vector_type(8))) short short8_t;
typedef __attribute__((ext_vector_type(4))) short short4_t;
typedef __attribute__((ext_vector_type(4))) float f32x4_t;

static __device__ __forceinline__ short f2bf(float f) {
  union { float f; unsigned u; } a;
  a.f = f;
  unsigned u = a.u;
  unsigned r = u + 0x7fffu + ((u >> 16) & 1u);  // RNE
  return (short)(r >> 16);
}

// ---------------- L1: 3 gate GEMMs + per-chunk scan summaries ----------------
// grid (64 mtiles, 4 ntiles), block 256. layer0: stage A straight from the
// embedding gather (emb f32 -> bf16) and write x (nt-partitioned cols).
__global__ __launch_bounds__(256) void kL1(const short* __restrict__ xb,
                                           const int* __restrict__ ids,
                                           const float* __restrict__ emb,
                                           float* __restrict__ x,
                                           const float* __restrict__ Wi,
                                           const float* __restrict__ Wf,
                                           const float* __restrict__ Wg,
                                           const float* __restrict__ bi,
                                           const float* __restrict__ bfv,
                                           const float* __restrict__ bg,
                                           float* __restrict__ gall,
                                           float* __restrict__ P,
                                           float* __restrict__ S,
                                           float lower, int layer0) {
  __shared__ __align__(16) short Alds[64][264];
  __shared__ __align__(16) short Wlds[64][264];
  __shared__ __align__(16) float Ilds[64][68];
  __shared__ __align__(16) float Flds[64][68];
  __shared__ __align__(16) float bsh3[192];

  int tid = threadIdx.x;
  int mt = blockIdx.x, nt = blockIdx.y;
  int m0 = mt * 64, n0 = nt * 64;

  if (layer0) {
#pragma unroll
    for (int p = 0; p < 8; p++) {
      int idx = p * 256 + tid;
      int row = idx >> 5, ck = idx & 31;   // cols ck*8..ck*8+7
      int id = ids[m0 + row];
      float4 e0 = *(const float4*)(emb + (size_t)id * HH + ck * 8);
      float4 e1 = *(const float4*)(emb + (size_t)id * HH + ck * 8 + 4);
      short8_t a8;
      a8[0] = f2bf(e0.x); a8[1] = f2bf(e0.y); a8[2] = f2bf(e0.z); a8[3] = f2bf(e0.w);
      a8[4] = f2bf(e1.x); a8[5] = f2bf(e1.y); a8[6] = f2bf(e1.z); a8[7] = f2bf(e1.w);
      *(short8_t*)&Alds[row][ck * 8] = a8;
      if ((ck >> 3) == nt) {  // exact col partition across nt blocks
        *(float4*)(x + (size_t)(m0 + row) * HH + ck * 8) = e0;
        *(float4*)(x + (size_t)(m0 + row) * HH + ck * 8 + 4) = e1;
      }
    }
  } else {
#pragma unroll
    for (int p = 0; p < 8; p++) {
      int idx = p * 256 + tid;
      int row = idx >> 5, ck = idx & 31;
      *(short8_t*)&Alds[row][ck * 8] =
          *(const short8_t*)(xb + (size_t)(m0 + row) * HH + ck * 8);
    }
  }
  if (tid < 64) bsh3[tid] = bi[n0 + tid];
  else if (tid < 128) bsh3[tid] = bfv[n0 + tid - 64];
  else if (tid < 192) bsh3[tid] = bg[n0 + tid - 128];

  int lane = tid & 63, w = tid >> 6, wm = w >> 1, wn = w & 1;
  int r16 = lane & 15, kg = (lane >> 4) * 8;
  int cg = tid & 15, kr = tid >> 4;

  for (int gz = 0; gz < 3; gz++) {
    const float* W = (gz == 0) ? Wi : (gz == 1) ? Wf : Wg;
    float* dst = gall + (size_t)gz * (MM * HH);

    __syncthreads();  // Alds ready (iter0) / prev MFMA done with Wlds
#pragma unroll
    for (int p = 0; p < 16; p++) {
      int k = p * 16 + kr;
      float4 wv = *(const float4*)(W + (size_t)k * HH + n0 + cg * 4);
      Wlds[cg * 4 + 0][k] = f2bf(wv.x);
      Wlds[cg * 4 + 1][k] = f2bf(wv.y);
      Wlds[cg * 4 + 2][k] = f2bf(wv.z);
      Wlds[cg * 4 + 3][k] = f2bf(wv.w);
    }
    __syncthreads();

    f32x4_t acc[2][2] = {{{0.f,0.f,0.f,0.f},{0.f,0.f,0.f,0.f}},
                         {{0.f,0.f,0.f,0.f},{0.f,0.f,0.f,0.f}}};
#pragma unroll
    for (int kk = 0; kk < 8; kk++) {
      short8_t w0 = *(const short8_t*)&Wlds[wn * 32 + r16][kk * 32 + kg];
      short8_t w1 = *(const short8_t*)&Wlds[wn * 32 + 16 + r16][kk * 32 + kg];
      short8_t t0 = *(const short8_t*)&Alds[wm * 32 + r16][kk * 32 + kg];
      short8_t t1 = *(const short8_t*)&Alds[wm * 32 + 16 + r16][kk * 32 + kg];
      acc[0][0] = __builtin_amdgcn_mfma_f32_16x16x32_bf16(w0, t0, acc[0][0], 0, 0, 0);
      acc[0][1] = __builtin_amdgcn_mfma_f32_16x16x32_bf16(w0, t1, acc[0][1], 0, 0, 0);
      acc[1][0] = __builtin_amdgcn_mfma_f32_16x16x32_bf16(w1, t0, acc[1][0], 0, 0, 0);
      acc[1][1] = __builtin_amdgcn_mfma_f32_16x16x32_bf16(w1, t1, acc[1][1], 0, 0, 0);
    }
#pragma unroll
    for (int fv = 0; fv < 2; fv++)
#pragma unroll
      for (int ft = 0; ft < 2; ft++) {
        int tl = wm * 32 + ft * 16 + r16;                // token local 0..63
        int colb = wn * 32 + fv * 16 + (lane >> 4) * 4;  // h local 0..63
        f32x4_t z4 = acc[fv][ft] + *(const f32x4_t*)&bsh3[gz * 64 + colb];
        f32x4_t a4;
#pragma unroll
        for (int r = 0; r < 4; r++) {
          float z = z4[r];
          if (gz == 0) {
            a4[r] = z / (1.f + __expf(-z));                      // silu
          } else if (gz == 1) {
            a4[r] = lower + (1.f - lower) / (1.f + __expf(-z));  // bounded forget
          } else {
            a4[r] = 1.f / (1.f + __expf(-z));                    // sigmoid
          }
        }
        *(f32x4_t*)&dst[(size_t)(m0 + tl) * HH + n0 + colb] = a4;
        if (gz == 0) *(f32x4_t*)&Ilds[tl][colb] = a4;
        else if (gz == 1) *(f32x4_t*)&Flds[tl][colb] = a4;
      }
  }
  __syncthreads();  // Ilds/Flds complete

  if (tid < 128) {
    int chunk = tid >> 6, hl = tid & 63;
    float p = 1.f, s = 0.f;
#pragma unroll
    for (int t = 0; t < 32; t++) {
      float fv = Flds[chunk * 32 + t][hl];
      float iv = Ilds[chunk * 32 + t][hl];
      s = fv * s + (1.f - fv) * iv;
      p *= fv;
    }
    int b = mt >> 4;
    int c = (mt & 15) * 2 + chunk;
    int idx = (b * 32 + c) * HH + n0 + hl;
    P[idx] = p;
    S[idx] = s;
  }
}

// ---------------- scan pass 2+3 fused ----------------
// grid 256 blocks (b, c, h-half), block 128: full CU coverage.
__global__ __launch_bounds__(128) void k_scan23(const float* __restrict__ gall,
                                                const float* __restrict__ P,
                                                const float* __restrict__ S,
                                                short* __restrict__ hgb,
                                                float* __restrict__ hid,
                                                int l) {
  int bid = blockIdx.x;
  int b = bid >> 6, c = (bid >> 1) & 31, half = bid & 1;
  int h = half * 128 + threadIdx.x;
  float hv = 0.f;
  for (int cc = 0; cc < c; cc++) {
    int idx = (b * 32 + cc) * HH + h;
    hv = P[idx] * hv + S[idx];
  }
  const float* iptr = gall;
  const float* fptr = gall + (size_t)MM * HH;
  const float* gptr = gall + (size_t)2 * MM * HH;
  size_t base = (size_t)(b * TT + c * 32) * HH + h;
#pragma unroll 8
  for (int t = 0; t < 32; t++) {
    float fv = fptr[base + (size_t)t * HH];
    float iv = iptr[base + (size_t)t * HH];
    float gv = gptr[base + (size_t)t * HH];
    hv = fv * hv + (1.f - fv) * iv;
    hgb[base + (size_t)t * HH] = f2bf(hv * gv);
  }
  if (c == 31) hid[(size_t)(l * BB + b) * HH + h] = hv;
}

// ---------------- out projection: x += hg @ Wo + bo; refresh xb ----------------
__global__ __launch_bounds__(256) void k_wo(const short* __restrict__ hgb,
                                            const float* __restrict__ W,
                                            const float* __restrict__ bias,
                                            float* __restrict__ x,
                                            short* __restrict__ xb) {
  __shared__ __align__(16) short Alds[64][264];
  __shared__ __align__(16) short Wlds[64][264];
  __shared__ __align__(16) float bsh[64];

  int tid = threadIdx.x;
  int m0 = blockIdx.x * 64, n0 = blockIdx.y * 64;

  int cg = tid & 15, kr = tid >> 4;
#pragma unroll
  for (int p = 0; p < 16; p++) {
    int k = p * 16 + kr;
    float4 wv = *(const float4*)(W + (size_t)k * HH + n0 + cg * 4);
    Wlds[cg * 4 + 0][k] = f2bf(wv.x);
    Wlds[cg * 4 + 1][k] = f2bf(wv.y);
    Wlds[cg * 4 + 2][k] = f2bf(wv.z);
    Wlds[cg * 4 + 3][k] = f2bf(wv.w);
  }
  if (tid < 64) bsh[tid] = bias[n0 + tid];
#pragma unroll
  for (int p = 0; p < 8; p++) {
    int idx = p * 256 + tid;
    int row = idx >> 5, ck = idx & 31;
    *(short8_t*)&Alds[row][ck * 8] =
        *(const short8_t*)(hgb + (size_t)(m0 + row) * HH + ck * 8);
  }
  __syncthreads();

  int lane = tid & 63, w = tid >> 6, wm = w >> 1, wn = w & 1;
  int r16 = lane & 15, kg = (lane >> 4) * 8;
  f32x4_t acc[2][2] = {{{0.f,0.f,0.f,0.f},{0.f,0.f,0.f,0.f}},
                       {{0.f,0.f,0.f,0.f},{0.f,0.f,0.f,0.f}}};
#pragma unroll
  for (int kk = 0; kk < 8; kk++) {
    short8_t w0 = *(const short8_t*)&Wlds[wn * 32 + r16][kk * 32 + kg];
    short8_t w1 = *(const short8_t*)&Wlds[wn * 32 + 16 + r16][kk * 32 + kg];
    short8_t t0 = *(const short8_t*)&Alds[wm * 32 + r16][kk * 32 + kg];
    short8_t t1 = *(const short8_t*)&Alds[wm * 32 + 16 + r16][kk * 32 + kg];
    acc[0][0] = __builtin_amdgcn_mfma_f32_16x16x32_bf16(w0, t0, acc[0][0], 0, 0, 0);
    acc[0][1] = __builtin_amdgcn_mfma_f32_16x16x32_bf16(w0, t1, acc[0][1], 0, 0, 0);
    acc[1][0] = __builtin_amdgcn_mfma_f32_16x16x32_bf16(w1, t0, acc[1][0], 0, 0, 0);
    acc[1][1] = __builtin_amdgcn_mfma_f32_16x16x32_bf16(w1, t1, acc[1][1], 0, 0, 0);
  }
#pragma unroll
  for (int fv = 0; fv < 2; fv++)
#pragma unroll
    for (int ft = 0; ft < 2; ft++) {
      int token = m0 + wm * 32 + ft * 16 + r16;
      int colb = wn * 32 + fv * 16 + (lane >> 4) * 4;
      size_t idx = (size_t)token * HH + n0 + colb;
      f32x4_t xv = *(const f32x4_t*)&x[idx];
      xv += acc[fv][ft] + *(const f32x4_t*)&bsh[colb];
      *(f32x4_t*)&x[idx] = xv;
      short4_t xb4;
#pragma unroll
      for (int r = 0; r < 4; r++) xb4[r] = f2bf(xv[r]);
      *(short4_t*)&xb[idx] = xb4;
    }
}

// ---------------- final projection: out = xb @ Wp + bp ----------------
// R14's exact kernel: (196 supertiles, 2 msplits), block 512 (8 waves),
// 3-barrier loop, acc -> Ost transpose, 1KB-contiguous NT wave-stores.
__global__ __launch_bounds__(512) void k_proj(const short* __restrict__ xb,
                                              const float* __restrict__ Wp,
                                              const float* __restrict__ bp,
                                              float* __restrict__ out) {
  __shared__ __align__(16) short Alds[64][264];
  __shared__ __align__(16) float Ost[64][260];   // 66.6KB; W-stage reuses this
  __shared__ __align__(16) float bsh[256];

  short (*Wst)[264] = (short(*)[264])&Ost[0][0]; // 33.8KB fits inside Ost

  int tid = threadIdx.x;
  int n0 = blockIdx.x * 256;

  int lane = tid & 63, w = tid >> 6;        // 8 waves
  int wm = w >> 2, wq = w & 3;              // wm: token half (32), wq: col quarter (64)
  int r16 = lane & 15, kg = (lane >> 4) * 8;
  int cg = tid & 15, kr = tid >> 4;         // kr 0..31

  if (tid < 256) bsh[tid] = (n0 + tid < VV) ? bp[n0 + tid] : 0.f;

  // stage + hoist W: four 64-col slabs sequentially through Wst
  short8_t wf[8][4];
  for (int s = 0; s < 4; s++) {
    int c0 = n0 + s * 64;
    bool fullslab = (c0 + 64 <= VV);
#pragma unroll
    for (int p = 0; p < 8; p++) {
      int k = p * 32 + kr;
      if (fullslab) {
        float4 wv = *(const float4*)(Wp + (size_t)k * VV + c0 + cg * 4);
        Wst[cg * 4 + 0][k] = f2bf(wv.x);
        Wst[cg * 4 + 1][k] = f2bf(wv.y);
        Wst[cg * 4 + 2][k] = f2bf(wv.z);
        Wst[cg * 4 + 3][k] = f2bf(wv.w);
      } else {
        for (int j = 0; j < 4; j++) {
          int n = c0 + cg * 4 + j;
          float v = (n < VV) ? Wp[(size_t)k * VV + n] : 0.f;
          Wst[cg * 4 + j][k] = f2bf(v);
        }
      }
    }
    __syncthreads();
    if (wq == s) {
#pragma unroll
      for (int kk = 0; kk < 8; kk++)
#pragma unroll
        for (int cf = 0; cf < 4; cf++)
          wf[kk][cf] = *(const short8_t*)&Wst[cf * 16 + r16][kk * 32 + kg];
    }
    asm volatile("s_waitcnt lgkmcnt(0)" ::: "memory");
    __syncthreads();
  }

  int arow = tid >> 5;       // 0..15; A stage rows arow + 16p
  int ack = tid & 31;

  const int NMT = 32;  // 2 msplits * 32 * 64 = 4096 = MM
  int mbase = blockIdx.y * NMT * 64;

  short8_t areg[4];
#pragma unroll
  for (int p = 0; p < 4; p++)
    areg[p] = *(const short8_t*)(xb + (size_t)(mbase + p * 16 + arow) * HH + ack * 8);

  for (int mi = 0; mi < NMT; mi++) {
    int m0 = mbase + mi * 64;

    // barrier A: prev MFMA done with Alds; prev readout done with Ost.
    __builtin_amdgcn_sched_barrier(0);
    __builtin_amdgcn_s_barrier();
    __builtin_amdgcn_sched_barrier(0);

#pragma unroll
    for (int p = 0; p < 4; p++)
      *(short8_t*)&Alds[p * 16 + arow][ack * 8] = areg[p];

    // barrier B: Alds visible; lgkmcnt only (NT stores keep streaming).
    asm volatile("s_waitcnt lgkmcnt(0)" ::: "memory");
    __builtin_amdgcn_sched_barrier(0);
    __builtin_amdgcn_s_barrier();
    __builtin_amdgcn_sched_barrier(0);

    if (mi + 1 < NMT) {
      int m1 = m0 + 64;
#pragma unroll
      for (int p = 0; p < 4; p++)
        areg[p] = *(const short8_t*)(xb + (size_t)(m1 + p * 16 + arow) * HH + ack * 8);
    }

    f32x4_t acc[2][4] = {{{0.f,0.f,0.f,0.f},{0.f,0.f,0.f,0.f},
                          {0.f,0.f,0.f,0.f},{0.f,0.f,0.f,0.f}},
                         {{0.f,0.f,0.f,0.f},{0.f,0.f,0.f,0.f},
                          {0.f,0.f,0.f,0.f},{0.f,0.f,0.f,0.f}}};
#pragma unroll
    for (int kk = 0; kk < 8; kk++) {
      short8_t t0 = *(const short8_t*)&Alds[wm * 32 + r16][kk * 32 + kg];
      short8_t t1 = *(const short8_t*)&Alds[wm * 32 + 16 + r16][kk * 32 + kg];
#pragma unroll
      for (int cf = 0; cf < 4; cf++) {
        acc[0][cf] = __builtin_amdgcn_mfma_f32_16x16x32_bf16(wf[kk][cf], t0, acc[0][cf], 0, 0, 0);
        acc[1][cf] = __builtin_amdgcn_mfma_f32_16x16x32_bf16(wf[kk][cf], t1, acc[1][cf], 0, 0, 0);
      }
    }

    // epilogue: stage acc into Ost[tok][col]
#pragma unroll
    for (int ft = 0; ft < 2; ft++)
#pragma unroll
      for (int cf = 0; cf < 4; cf++) {
        int tok = wm * 32 + ft * 16 + r16;
        int col = wq * 64 + cf * 16 + (lane >> 4) * 4;
        *(f32x4_t*)&Ost[tok][col] = acc[ft][cf];
      }
    // barrier C: Ost visible; lgkmcnt only.
    asm volatile("s_waitcnt lgkmcnt(0)" ::: "memory");
    __builtin_amdgcn_sched_barrier(0);
    __builtin_amdgcn_s_barrier();
    __builtin_amdgcn_sched_barrier(0);

    // readout: wave w covers rows w*8..w*8+7; each wave-store instruction
    // writes ONE ROW x 1KB contiguous (64 lanes x 16B).
    int colc = lane * 4;
    bool colok = (n0 + colc < VV);
#pragma unroll
    for (int r = 0; r < 8; r++) {
      int row = w * 8 + r;
      f32x4_t v = *(const f32x4_t*)&Ost[row][colc] + *(const f32x4_t*)&bsh[colc];
      if (colok)
        __builtin_nontemporal_store(v,
            (f32x4_t*)(out + (size_t)(m0 + row) * VV + n0 + colc));
    }
  }
}

extern "C" void kernel_launch(void* const* d_in, const int* in_sizes, int n_in,
                              void* d_out, int out_size, void* d_ws, size_t ws_size,
                              hipStream_t stream) {
  const int* ids = (const int*)d_in[0];
  const float* emb = (const float*)d_in[1];
  const float* Wi = (const float*)d_in[2];
  const float* bi = (const float*)d_in[3];
  const float* Wf = (const float*)d_in[4];
  const float* bfv = (const float*)d_in[5];
  const float* Wg = (const float*)d_in[6];
  const float* bg = (const float*)d_in[7];
  const float* Wo = (const float*)d_in[8];
  const float* bo = (const float*)d_in[9];
  const float* Wp = (const float*)d_in[10];
  const float* bp = (const float*)d_in[11];
  float* out = (float*)d_out;

  // workspace layout (~20.5 MB)
  char* w = (char*)d_ws;
  float* x = (float*)(w);                          // 4 MB
  short* xb = (short*)(w + (4u << 20));            // 2 MB
  float* gall = (float*)(w + (6u << 20));          // 12 MB: [3][4096][256] (i,f,g)
  short* hgb = (short*)(w + (18u << 20));          // 2 MB
  float* Parr = (float*)(w + (20u << 20));         // 128 KB
  float* Sarr = (float*)(w + (20u << 20) + (128u << 10));
  float* hid = out + HID_OFF;

  for (int l = 0; l < LL; l++) {
    float lower = (float)l / (float)LL;
    kL1<<<dim3(64, 4), 256, 0, stream>>>(
        xb, ids, emb, x,
        Wi + (size_t)l * HH * HH, Wf + (size_t)l * HH * HH,
        Wg + (size_t)l * HH * HH, bi + l * HH, bfv + l * HH, bg + l * HH,
        gall, Parr, Sarr, lower, l == 0 ? 1 : 0);
    k_scan23<<<256, 128, 0, stream>>>(gall, Parr, Sarr, hgb, hid, l);
    k_wo<<<dim3(64, 4), 256, 0, stream>>>(hgb, Wo + (size_t)l * HH * HH,
                                          bo + l * HH, x, xb);
  }

  k_proj<<<dim3(196, 2), 512, 0, stream>>>(xb, Wp, bp, out);
}